// Round 14
// baseline (1955.290 us; speedup 1.0000x reference)
//
#include <hip/hip_runtime.h>

#define VOX (128*128*32)   // 524288 voxels
#define CCH 64
#define NCL 20
#define DD 128
#define HH 128
#define WW 32
#define ZT 8
#define EPSV 1e-5f
#define THRESV 0.2f

// ---- order-preserving float <-> uint key for atomic min/max ----
__device__ __forceinline__ unsigned keyOf(float f){
    unsigned u = __float_as_uint(f);
    return (u & 0x80000000u) ? ~u : (u | 0x80000000u);
}
__device__ __forceinline__ float keyInv(unsigned k){
    unsigned u = (k & 0x80000000u) ? (k & 0x7fffffffu) : ~k;
    return __uint_as_float(u);
}

__global__ void k_init(unsigned* keys, float* zpg){
    int i = threadIdx.x;
    if (i < NCL){ keys[i] = 0xFFFFFFFFu; keys[NCL+i] = 0u; }
    #pragma unroll
    for (int k = 0; k < 4; ++k) zpg[k*64 + i] = 0.f;
}

// ---- Pass A: logit + softmax + per-voxel mean/max, 4 voxels/thread (float4) ----
__global__ __launch_bounds__(256, 4) void k_logit_softmax(
    const float* __restrict__ x, const float* __restrict__ clsw,
    const float* __restrict__ clsb, float* __restrict__ masks,
    float* __restrict__ logit, float* __restrict__ mx, float* __restrict__ Mx)
{
    __shared__ float sw[NCL*CCH];
    __shared__ float sb[NCL];
    int tid = threadIdx.x;
    for (int q = tid; q < NCL*CCH; q += 256) sw[q] = clsw[q];
    if (tid < NCL) sb[tid] = clsb[tid];
    __syncthreads();
    const int v = blockIdx.x*1024 + tid*4;
    float4 acc[NCL];
    #pragma unroll
    for (int o=0;o<NCL;o++){ float b = sb[o]; acc[o] = make_float4(b,b,b,b); }
    float4 s  = make_float4(0.f,0.f,0.f,0.f);
    float4 mm = make_float4(-1e30f,-1e30f,-1e30f,-1e30f);
    #pragma unroll 4
    for (int c=0;c<CCH;c++){
        float4 xv = *(const float4*)&x[(size_t)c*VOX + v];
        s.x += xv.x; s.y += xv.y; s.z += xv.z; s.w += xv.w;
        mm.x = fmaxf(mm.x, xv.x); mm.y = fmaxf(mm.y, xv.y);
        mm.z = fmaxf(mm.z, xv.z); mm.w = fmaxf(mm.w, xv.w);
        #pragma unroll
        for (int o=0;o<NCL;o++){
            float w = sw[o*CCH + c];
            acc[o].x = fmaf(xv.x, w, acc[o].x);
            acc[o].y = fmaf(xv.y, w, acc[o].y);
            acc[o].z = fmaf(xv.z, w, acc[o].z);
            acc[o].w = fmaf(xv.w, w, acc[o].w);
        }
    }
    *(float4*)&mx[v] = make_float4(s.x*(1.f/64.f), s.y*(1.f/64.f), s.z*(1.f/64.f), s.w*(1.f/64.f));
    *(float4*)&Mx[v] = mm;
    float4 lm = acc[0];
    #pragma unroll
    for (int o=1;o<NCL;o++){
        lm.x = fmaxf(lm.x, acc[o].x); lm.y = fmaxf(lm.y, acc[o].y);
        lm.z = fmaxf(lm.z, acc[o].z); lm.w = fmaxf(lm.w, acc[o].w);
    }
    float4 es = make_float4(0.f,0.f,0.f,0.f);
    #pragma unroll
    for (int o=0;o<NCL;o++){
        *(float4*)&logit[(size_t)o*VOX + v] = acc[o];
        float4 e;
        e.x = expf(acc[o].x - lm.x); e.y = expf(acc[o].y - lm.y);
        e.z = expf(acc[o].z - lm.z); e.w = expf(acc[o].w - lm.w);
        es.x += e.x; es.y += e.y; es.z += e.z; es.w += e.w;
        acc[o] = e;
    }
    float4 inv = make_float4(1.f/es.x, 1.f/es.y, 1.f/es.z, 1.f/es.w);
    #pragma unroll
    for (int o=0;o<NCL;o++){
        float4 r;
        r.x = acc[o].x*inv.x; r.y = acc[o].y*inv.y;
        r.z = acc[o].z*inv.z; r.w = acc[o].w*inv.w;
        *(float4*)&masks[(size_t)o*VOX + v] = r;
    }
}

// ---- Pass B: 32x32 tile, 4-wave blocks, fused finalize, setprio on FMA body ----
#define F4(A, WV, q0,q1,q2,q3) { A.x=fmaf(q0,WV,A.x); A.y=fmaf(q1,WV,A.y); \
                                 A.z=fmaf(q2,WV,A.z); A.w=fmaf(q3,WV,A.w); }
#define DZ4(A, WP, P) { \
    F4(A,(WP)[0], P##0,P##1,P##2,P##3) \
    F4(A,(WP)[1], P##1,P##2,P##3,P##4) \
    F4(A,(WP)[2], P##2,P##3,P##4,P##5) \
    F4(A,(WP)[3], P##3,P##4,P##5,P##6) \
    F4(A,(WP)[4], P##4,P##5,P##6,P##7) \
    F4(A,(WP)[5], P##5,P##6,P##7,P##8) \
    F4(A,(WP)[6], P##6,P##7,P##8,P##9) }

#define TGROUP4(P, WT) { \
    const float* wd_ = (WT) + dy*7; \
    if (ok6) DZ4(a6, wd_+0,   P) \
    if (ok5) DZ4(a5, wd_+49,  P) \
    if (ok4) DZ4(a4, wd_+98,  P) \
    if (ok3) DZ4(a3, wd_+147, P) \
    if (ok2) DZ4(a2, wd_+196, P) \
    if (ok1) DZ4(a1, wd_+245, P) \
    if (ok0) DZ4(a0, wd_+294, P) }

#define PLANE_F 1280     // 40 rows x 32 floats
#define BUF_F   3840     // 3 planes
#define LDS_F   7680     // 2 buffers

__device__ __forceinline__ void issue_slice(const float* mk, const float* mxp, const float* Mxp,
        const float* zpg, float* FLf, int bufF, int zi, int y0, int lane, int wid)
{
    const bool zok = (unsigned)zi < (unsigned)DD;
    const float* srcs[3] = { mk, mxp, Mxp };
    #pragma unroll
    for (int k = 0; k < 15; ++k){
        if ((k >> 2) != wid) continue;           // waves issue 4/4/4/3
        const int f = k/5, j = k%5;
        int Q   = j*64 + lane;
        int row = Q >> 3, xq = Q & 7;
        int gy  = y0 - 3 + row;
        const float* g;
        if (zok && row < 38 && (unsigned)gy < (unsigned)HH)
            g = srcs[f] + ((size_t)(zi*HH + gy)*32 + xq*4);
        else
            g = zpg + lane*4;
        float* l = FLf + bufF + f*PLANE_F + j*256;   // wave-uniform; HW adds lane*16B
        __builtin_amdgcn_global_load_lds(
            (const __attribute__((address_space(1))) void*)g,
            (__attribute__((address_space(3))) void*)l, 16, 0, 0);
    }
}

__global__ __launch_bounds__(256, 5) void k_conv13(const float* __restrict__ masksAll,
        const float* __restrict__ mxp, const float* __restrict__ Mxp,
        const float* __restrict__ cfr, float* __restrict__ G,
        unsigned* __restrict__ keys, const float* __restrict__ zpg)
{
    __shared__ __align__(16) float FLf[LDS_F];
    __shared__ float r4[8];
    const int y0  = blockIdx.x * 32;
    const int z0  = blockIdx.y * ZT;
    const int cls = blockIdx.z;
    const int tid = threadIdx.x;
    const int lane = tid & 63, wid = tid >> 6;
    const int y  = tid >> 3;          // 0..31
    const int xg = tid & 7;           // 0..7
    const int x0 = xg * 4;
    const bool lo_inv = (xg == 0), hi_inv = (xg == 7);
    const float* mk   = masksAll + (size_t)cls * VOX;
    const float* wcls = cfr + cls*1029;          // uniform -> scalar loads
    float* Gc = G + (size_t)cls * VOX;

    issue_slice(mk, mxp, Mxp, zpg, FLf, 0,     z0-3, y0, lane, wid);
    issue_slice(mk, mxp, Mxp, zpg, FLf, BUF_F, z0-2, y0, lane, wid);

    float4 a0{},a1{},a2{},a3{},a4{},a5{},a6{};
    float4 g0m{},g0x{},g1m{},g1x{},g2m{},g2x{};  // 3-deep (m, mx) capture pipeline
    float hmn = 1e30f, hmx = -1e30f;
    int cur = 0;

    #pragma unroll 1
    for (int zi = z0 - 3; zi <= z0 + ZT + 2; ++zi){
        // exact wait: leave next-slice loads (+1 store once storing started) in flight
        const bool pst = (zi >= z0 + 4);
        if (wid == 3){ if (pst) asm volatile("s_waitcnt vmcnt(4)" ::: "memory");
                       else     asm volatile("s_waitcnt vmcnt(3)" ::: "memory"); }
        else         { if (pst) asm volatile("s_waitcnt vmcnt(5)" ::: "memory");
                       else     asm volatile("s_waitcnt vmcnt(4)" ::: "memory"); }
        __builtin_amdgcn_sched_barrier(0);
        __builtin_amdgcn_s_barrier();
        __builtin_amdgcn_sched_barrier(0);

        const bool cap = (zi >= z0 && zi < z0 + ZT);   // capture m/mx for plane zi
        float4 nm{}, nx{};

        const int lo = z0 + 3 - zi;                // okJ: J>=lo && J-lo<ZT (wave-uniform)
        const bool ok0 = (0>=lo) && (0-lo<ZT);
        const bool ok1 = (1>=lo) && (1-lo<ZT);
        const bool ok2 = (2>=lo) && (2-lo<ZT);
        const bool ok3 = (3>=lo) && (3-lo<ZT);
        const bool ok4 = (4>=lo) && (4-lo<ZT);
        const bool ok5 = (5>=lo) && (5-lo<ZT);
        const bool ok6 = (6>=lo) && (6-lo<ZT);

        __builtin_amdgcn_s_setprio(1);
        #pragma unroll 1
        for (int dy = 0; dy < 7; ++dy){
            const int r = y + dy;
            const float* Pm = FLf + cur*BUF_F + r*32;
            const float* Pa = Pm + PLANE_F;
            const float* Pb = Pa + PLANE_F;
            const int c0 = (xg > 0 ? xg-1 : 0)*4;
            const int c1 = xg*4;
            const int c2 = (xg < 7 ? xg+1 : 7)*4;
            const float4 M0 = *(const float4*)(Pm + c0);
            const float4 M1 = *(const float4*)(Pm + c1);
            const float4 M2 = *(const float4*)(Pm + c2);
            if (cap && dy == 3) nm = M1;            // M1 IS m[zi][y0+y][x0..x0+3]
            const float pm0 = lo_inv ? 0.f : M0.y;
            const float pm1 = lo_inv ? 0.f : M0.z;
            const float pm2 = lo_inv ? 0.f : M0.w;
            const float pm3 = M1.x, pm4 = M1.y, pm5 = M1.z, pm6 = M1.w;
            const float pm7 = hi_inv ? 0.f : M2.x;
            const float pm8 = hi_inv ? 0.f : M2.y;
            const float pm9 = hi_inv ? 0.f : M2.z;

            {   // t = 0: field mask*mx
                const float4 A0 = *(const float4*)(Pa + c0);
                const float4 A1 = *(const float4*)(Pa + c1);
                const float4 A2 = *(const float4*)(Pa + c2);
                if (cap && dy == 3) nx = A1;        // A1 IS mx[...]
                const float pa0 = pm0*A0.y, pa1 = pm1*A0.z, pa2 = pm2*A0.w;
                const float pa3 = pm3*A1.x, pa4 = pm4*A1.y, pa5 = pm5*A1.z, pa6 = pm6*A1.w;
                const float pa7 = pm7*A2.x, pa8 = pm8*A2.y, pa9 = pm9*A2.z;
                TGROUP4(pa, wcls)
            }
            {   // t = 1: field mask*Mx
                const float4 B0 = *(const float4*)(Pb + c0);
                const float4 B1 = *(const float4*)(Pb + c1);
                const float4 B2 = *(const float4*)(Pb + c2);
                const float pb0 = pm0*B0.y, pb1 = pm1*B0.z, pb2 = pm2*B0.w;
                const float pb3 = pm3*B1.x, pb4 = pm4*B1.y, pb5 = pm5*B1.z, pb6 = pm6*B1.w;
                const float pb7 = pm7*B2.x, pb8 = pm8*B2.y, pb9 = pm9*B2.z;
                TGROUP4(pb, wcls + 343)
            }
            // t = 2: field mask
            TGROUP4(pm, wcls + 686)
        }
        __builtin_amdgcn_s_setprio(0);

        __builtin_amdgcn_sched_barrier(0);
        __builtin_amdgcn_s_barrier();            // all waves done reading buf[cur]
        __builtin_amdgcn_sched_barrier(0);
        issue_slice(mk, mxp, Mxp, zpg, FLf, cur*BUF_F, zi+2, y0, lane, wid);
        __builtin_amdgcn_sched_barrier(0);

        if (zi >= z0 + 3){                       // finalize plane zo = zi-3 from saved regs
            const int zo = zi - 3;
            const int oidx = (zo*HH + (y0 + y))*WW + x0;
            float4 r1;
            r1.x = g0m.x/(1.f + expf(-a0.x));
            r1.y = g0m.y/(1.f + expf(-a0.y));
            r1.z = g0m.z/(1.f + expf(-a0.z));
            r1.w = g0m.w/(1.f + expf(-a0.w));
            *(float4*)(Gc + oidx) = r1;          // store AFTER issues (vmcnt order)
            float h0 = r1.x*g0x.x, h1 = r1.y*g0x.y, h2 = r1.z*g0x.z, h3 = r1.w*g0x.w;
            hmn = fminf(hmn, fminf(fminf(h0,h1), fminf(h2,h3)));
            hmx = fmaxf(hmx, fmaxf(fmaxf(h0,h1), fmaxf(h2,h3)));
        }
        // rotate accumulators and capture pipeline
        a0=a1; a1=a2; a2=a3; a3=a4; a4=a5; a5=a6;
        a6 = make_float4(0.f,0.f,0.f,0.f);
        g0m=g1m; g0x=g1x; g1m=g2m; g1x=g2x; g2m=nm; g2x=nx;
        cur ^= 1;
    }
    asm volatile("s_waitcnt vmcnt(0)" ::: "memory");  // drain dummy DMA before LDS dealloc

    #pragma unroll
    for (int off = 32; off > 0; off >>= 1){
        hmn = fminf(hmn, __shfl_xor(hmn, off));
        hmx = fmaxf(hmx, __shfl_xor(hmx, off));
    }
    if ((tid & 63) == 0){ r4[wid*2] = hmn; r4[wid*2+1] = hmx; }
    __syncthreads();
    if (tid == 0){
        float a = fminf(fminf(r4[0],r4[2]), fminf(r4[4],r4[6]));
        float b = fmaxf(fmaxf(r4[1],r4[3]), fmaxf(r4[5],r4[7]));
        atomicMin(&keys[cls],     keyOf(a));
        atomicMax(&keys[NCL+cls], keyOf(b));
    }
}

__global__ void k_thr(const unsigned* __restrict__ keys, float* __restrict__ hminA,
                      float* __restrict__ invR){
    int i = threadIdx.x;
    if (i < NCL){
        float hm = keyInv(keys[i]);
        float hM = keyInv(keys[NCL+i]);
        hminA[i] = hm;
        invR[i] = 1.f/(hM - hm);
    }
}

// ---- fused region + stats: g = ma*(norm>0.2) computed inline, written back to G,
// and S1/S2 accumulated in the same pass. Values bitwise-identical to the split
// kernels (same formulas, same summation order). Saves a full 86 MB G pass.
__global__ __launch_bounds__(256) void k_statsr(const float* __restrict__ x,
        float* G, const float* __restrict__ mxp,
        const float* __restrict__ hminA, const float* __restrict__ invR,
        float* __restrict__ part)
{
    __shared__ float xt[64][65];
    __shared__ float sA[NCL], sR[NCL];
    int tid = threadIdx.x;
    if (tid < NCL){ sA[tid] = hminA[tid]; sR[tid] = invR[tid]; }
    int c = tid & 63, vg = tid >> 6;
    int v0 = blockIdx.x * 1024;
    const int cc = tid >> 2;
    const int u0 = (tid & 3) * 16;
    float s1[NCL], s2[NCL];
    #pragma unroll
    for (int i=0;i<NCL;i++){ s1[i]=0.f; s2[i]=0.f; }
    #pragma unroll 1
    for (int t = 0; t < 16; ++t){
        int vb = v0 + t*64;
        __syncthreads();
        float ld[16];
        #pragma unroll
        for (int j = 0; j < 4; ++j){
            float4 f4 = *(const float4*)&x[(size_t)cc*VOX + vb + u0 + j*4];
            ld[j*4+0]=f4.x; ld[j*4+1]=f4.y; ld[j*4+2]=f4.z; ld[j*4+3]=f4.w;
        }
        #pragma unroll
        for (int j = 0; j < 16; ++j) xt[u0 + j][cc] = ld[j];
        __syncthreads();
        #pragma unroll 1
        for (int k = 0; k < 16; ++k){
            int vv = (k<<2) + vg;
            float xv  = xt[vv][c];
            float mxv = mxp[vb + vv];
            #pragma unroll
            for (int i=0;i<NCL;i++){
                float ma = G[i*VOX + vb + vv];
                float norm = (ma*mxv - sA[i]) * sR[i];
                float g = (norm > THRESV) ? ma : 0.f;
                if (c == 0) G[i*VOX + vb + vv] = g;   // one lane per vg writes
                float p = xv * g;
                s1[i] += p;
                s2[i] = fmaf(p, p, s2[i]);
            }
        }
    }
    __shared__ float red[4][64][2*NCL];
    #pragma unroll
    for (int i=0;i<NCL;i++){ red[vg][c][i] = s1[i]; red[vg][c][NCL+i] = s2[i]; }
    __syncthreads();
    if (vg == 0){
        float* dst = part + (size_t)blockIdx.x * (NCL*CCH*2);
        for (int i=0;i<NCL;i++){
            float a = red[0][c][i]+red[1][c][i]+red[2][c][i]+red[3][c][i];
            float b = red[0][c][NCL+i]+red[1][c][NCL+i]+red[2][c][NCL+i]+red[3][c][NCL+i];
            dst[i*CCH*2 + c*2 + 0] = a;
            dst[i*CCH*2 + c*2 + 1] = b;
        }
    }
}

// ---- finish stats over 512 partials ----
__global__ void k_params(const float* __restrict__ part, const float* __restrict__ gamma,
        const float* __restrict__ beta, float* __restrict__ aArr, float* __restrict__ kcArr)
{
    int i = blockIdx.x, c = threadIdx.x;
    float s1 = 0.f, s2 = 0.f;
    for (int b=0;b<512;b++){
        const float* p = part + (size_t)b*(NCL*CCH*2) + i*CCH*2 + c*2;
        s1 += p[0]; s2 += p[1];
    }
    float m   = s1 * (1.f/(float)VOX);
    float var = s2 * (1.f/(float)VOX) - m*m;
    float rinv = 1.f/sqrtf(var + EPSV);
    float gm = gamma[c];
    aArr[i*CCH + c]  = gm*rinv;
    kcArr[i*CCH + c] = beta[c] - m*rinv*gm;
}

__global__ void k_kcol(const float* __restrict__ kcArr, float* __restrict__ KcA){
    int c = threadIdx.x;
    if (c < CCH){
        float s = 0.f;
        for (int i=0;i<NCL;i++) s += kcArr[i*CCH + c];
        KcA[c] = s;
    }
}

// ---- final: 2 voxels/thread ----
__global__ __launch_bounds__(256) void k_final(const float* __restrict__ x,
        float* outAll, const float* __restrict__ aArr, const float* __restrict__ KcA)
{
    __shared__ float aL[NCL*CCH];
    __shared__ float KL[CCH];
    int tid = threadIdx.x;
    for (int q=tid; q<NCL*CCH; q+=256) aL[q] = aArr[q];
    if (tid < CCH) KL[tid] = KcA[tid];
    __syncthreads();
    int v = blockIdx.x*512 + tid;     // voxels v and v+256
    const float* Gp = outAll + (size_t)NCL*VOX;
    float g[NCL], h[NCL];
    #pragma unroll
    for (int i=0;i<NCL;i++){ g[i] = Gp[i*VOX + v]; h[i] = Gp[i*VOX + v + 256]; }
    #pragma unroll 4
    for (int c=0;c<CCH;c++){
        float P0 = 0.f, P1 = 0.f;
        #pragma unroll
        for (int i=0;i<NCL;i++){
            float a = aL[i*CCH + c];
            P0 = fmaf(g[i], a, P0);
            P1 = fmaf(h[i], a, P1);
        }
        float kl = KL[c];
        float xv0 = x[c*VOX + v];
        float xv1 = x[c*VOX + v + 256];
        outAll[c*VOX + v]       = fmaxf(0.f, fmaf(xv0, P0, kl));
        outAll[c*VOX + v + 256] = fmaxf(0.f, fmaf(xv1, P1, kl));
    }
}

extern "C" void kernel_launch(void* const* d_in, const int* in_sizes, int n_in,
                              void* d_out, int out_size, void* d_ws, size_t ws_size,
                              hipStream_t stream)
{
    const float* x     = (const float*)d_in[0];
    const float* clsw  = (const float*)d_in[1];
    const float* clsb  = (const float*)d_in[2];
    const float* cfr   = (const float*)d_in[3];
    const float* gamma = (const float*)d_in[4];
    const float* beta  = (const float*)d_in[5];

    float* out   = (float*)d_out;
    float* logit = out + (size_t)CCH*VOX;     // second output
    float* masks = out;                       // scratch: out[0 .. 20V)
    float* G     = out + (size_t)NCL*VOX;     // scratch: out[20V .. 40V)

    float* ws    = (float*)d_ws;
    float* mxp   = ws;                        // V
    float* Mxp   = ws + VOX;                  // V
    unsigned* keys = (unsigned*)(ws + 2*(size_t)VOX);   // 40
    float* hminA = ws + 2*(size_t)VOX + 64;   // 20
    float* invR  = hminA + NCL;               // 20
    float* part  = ws + 2*(size_t)VOX + 128;  // 512*2560
    float* aArr  = part + 512*(NCL*CCH*2);    // 1280
    float* kcArr = aArr + NCL*CCH;            // 1280
    float* KcA   = kcArr + NCL*CCH;           // 64
    float* zpg   = KcA + CCH;                 // 256 (zero page for OOB lanes)

    k_init<<<1, 64, 0, stream>>>(keys, zpg);
    k_logit_softmax<<<VOX/1024, 256, 0, stream>>>(x, clsw, clsb, masks, logit, mxp, Mxp);
    k_conv13<<<dim3(4, 16, NCL), 256, 0, stream>>>(masks, mxp, Mxp, cfr, G, keys, zpg);
    k_thr<<<1, 32, 0, stream>>>(keys, hminA, invR);
    k_statsr<<<512, 256, 0, stream>>>(x, G, mxp, hminA, invR, part);
    k_params<<<NCL, CCH, 0, stream>>>(part, gamma, beta, aArr, kcArr);
    k_kcol<<<1, CCH, 0, stream>>>(kcArr, KcA);
    k_final<<<VOX/512, 256, 0, stream>>>(x, out, aArr, KcA);
}

// Round 15
// 1098.280 us; speedup vs baseline: 1.7803x; 1.7803x over previous
//
#include <hip/hip_runtime.h>

#define VOX (128*128*32)   // 524288 voxels
#define CCH 64
#define NCL 20
#define DD 128
#define HH 128
#define WW 32
#define ZT 8
#define EPSV 1e-5f
#define THRESV 0.2f

// ---- order-preserving float <-> uint key for atomic min/max ----
__device__ __forceinline__ unsigned keyOf(float f){
    unsigned u = __float_as_uint(f);
    return (u & 0x80000000u) ? ~u : (u | 0x80000000u);
}
__device__ __forceinline__ float keyInv(unsigned k){
    unsigned u = (k & 0x80000000u) ? (k & 0x7fffffffu) : ~k;
    return __uint_as_float(u);
}

__global__ void k_init(unsigned* keys, float* zpg){
    int i = threadIdx.x;
    if (i < NCL){ keys[i] = 0xFFFFFFFFu; keys[NCL+i] = 0u; }
    #pragma unroll
    for (int k = 0; k < 4; ++k) zpg[k*64 + i] = 0.f;
}

// ---- Pass A: logit + softmax + per-voxel mean/max, 4 voxels/thread (float4) ----
__global__ __launch_bounds__(256, 4) void k_logit_softmax(
    const float* __restrict__ x, const float* __restrict__ clsw,
    const float* __restrict__ clsb, float* __restrict__ masks,
    float* __restrict__ logit, float* __restrict__ mx, float* __restrict__ Mx)
{
    __shared__ float sw[NCL*CCH];
    __shared__ float sb[NCL];
    int tid = threadIdx.x;
    for (int q = tid; q < NCL*CCH; q += 256) sw[q] = clsw[q];
    if (tid < NCL) sb[tid] = clsb[tid];
    __syncthreads();
    const int v = blockIdx.x*1024 + tid*4;
    float4 acc[NCL];
    #pragma unroll
    for (int o=0;o<NCL;o++){ float b = sb[o]; acc[o] = make_float4(b,b,b,b); }
    float4 s  = make_float4(0.f,0.f,0.f,0.f);
    float4 mm = make_float4(-1e30f,-1e30f,-1e30f,-1e30f);
    #pragma unroll 4
    for (int c=0;c<CCH;c++){
        float4 xv = *(const float4*)&x[(size_t)c*VOX + v];
        s.x += xv.x; s.y += xv.y; s.z += xv.z; s.w += xv.w;
        mm.x = fmaxf(mm.x, xv.x); mm.y = fmaxf(mm.y, xv.y);
        mm.z = fmaxf(mm.z, xv.z); mm.w = fmaxf(mm.w, xv.w);
        #pragma unroll
        for (int o=0;o<NCL;o++){
            float w = sw[o*CCH + c];
            acc[o].x = fmaf(xv.x, w, acc[o].x);
            acc[o].y = fmaf(xv.y, w, acc[o].y);
            acc[o].z = fmaf(xv.z, w, acc[o].z);
            acc[o].w = fmaf(xv.w, w, acc[o].w);
        }
    }
    *(float4*)&mx[v] = make_float4(s.x*(1.f/64.f), s.y*(1.f/64.f), s.z*(1.f/64.f), s.w*(1.f/64.f));
    *(float4*)&Mx[v] = mm;
    float4 lm = acc[0];
    #pragma unroll
    for (int o=1;o<NCL;o++){
        lm.x = fmaxf(lm.x, acc[o].x); lm.y = fmaxf(lm.y, acc[o].y);
        lm.z = fmaxf(lm.z, acc[o].z); lm.w = fmaxf(lm.w, acc[o].w);
    }
    float4 es = make_float4(0.f,0.f,0.f,0.f);
    #pragma unroll
    for (int o=0;o<NCL;o++){
        *(float4*)&logit[(size_t)o*VOX + v] = acc[o];
        float4 e;
        e.x = expf(acc[o].x - lm.x); e.y = expf(acc[o].y - lm.y);
        e.z = expf(acc[o].z - lm.z); e.w = expf(acc[o].w - lm.w);
        es.x += e.x; es.y += e.y; es.z += e.z; es.w += e.w;
        acc[o] = e;
    }
    float4 inv = make_float4(1.f/es.x, 1.f/es.y, 1.f/es.z, 1.f/es.w);
    #pragma unroll
    for (int o=0;o<NCL;o++){
        float4 r;
        r.x = acc[o].x*inv.x; r.y = acc[o].y*inv.y;
        r.z = acc[o].z*inv.z; r.w = acc[o].w*inv.w;
        *(float4*)&masks[(size_t)o*VOX + v] = r;
    }
}

// ---- Pass B: 32x32 tile, 4-wave blocks, fused finalize, setprio on FMA body ----
#define F4(A, WV, q0,q1,q2,q3) { A.x=fmaf(q0,WV,A.x); A.y=fmaf(q1,WV,A.y); \
                                 A.z=fmaf(q2,WV,A.z); A.w=fmaf(q3,WV,A.w); }
#define DZ4(A, WP, P) { \
    F4(A,(WP)[0], P##0,P##1,P##2,P##3) \
    F4(A,(WP)[1], P##1,P##2,P##3,P##4) \
    F4(A,(WP)[2], P##2,P##3,P##4,P##5) \
    F4(A,(WP)[3], P##3,P##4,P##5,P##6) \
    F4(A,(WP)[4], P##4,P##5,P##6,P##7) \
    F4(A,(WP)[5], P##5,P##6,P##7,P##8) \
    F4(A,(WP)[6], P##6,P##7,P##8,P##9) }

#define TGROUP4(P, WT) { \
    const float* wd_ = (WT) + dy*7; \
    if (ok6) DZ4(a6, wd_+0,   P) \
    if (ok5) DZ4(a5, wd_+49,  P) \
    if (ok4) DZ4(a4, wd_+98,  P) \
    if (ok3) DZ4(a3, wd_+147, P) \
    if (ok2) DZ4(a2, wd_+196, P) \
    if (ok1) DZ4(a1, wd_+245, P) \
    if (ok0) DZ4(a0, wd_+294, P) }

#define PLANE_F 1280     // 40 rows x 32 floats
#define BUF_F   3840     // 3 planes
#define LDS_F   7680     // 2 buffers

__device__ __forceinline__ void issue_slice(const float* mk, const float* mxp, const float* Mxp,
        const float* zpg, float* FLf, int bufF, int zi, int y0, int lane, int wid)
{
    const bool zok = (unsigned)zi < (unsigned)DD;
    const float* srcs[3] = { mk, mxp, Mxp };
    #pragma unroll
    for (int k = 0; k < 15; ++k){
        if ((k >> 2) != wid) continue;           // waves issue 4/4/4/3
        const int f = k/5, j = k%5;
        int Q   = j*64 + lane;
        int row = Q >> 3, xq = Q & 7;
        int gy  = y0 - 3 + row;
        const float* g;
        if (zok && row < 38 && (unsigned)gy < (unsigned)HH)
            g = srcs[f] + ((size_t)(zi*HH + gy)*32 + xq*4);
        else
            g = zpg + lane*4;
        float* l = FLf + bufF + f*PLANE_F + j*256;   // wave-uniform; HW adds lane*16B
        __builtin_amdgcn_global_load_lds(
            (const __attribute__((address_space(1))) void*)g,
            (__attribute__((address_space(3))) void*)l, 16, 0, 0);
    }
}

__global__ __launch_bounds__(256, 5) void k_conv13(const float* __restrict__ masksAll,
        const float* __restrict__ mxp, const float* __restrict__ Mxp,
        const float* __restrict__ cfr, float* __restrict__ G,
        unsigned* __restrict__ keys, const float* __restrict__ zpg)
{
    __shared__ __align__(16) float FLf[LDS_F];
    __shared__ float r4[8];
    const int y0  = blockIdx.x * 32;
    const int z0  = blockIdx.y * ZT;
    const int cls = blockIdx.z;
    const int tid = threadIdx.x;
    const int lane = tid & 63, wid = tid >> 6;
    const int y  = tid >> 3;          // 0..31
    const int xg = tid & 7;           // 0..7
    const int x0 = xg * 4;
    const bool lo_inv = (xg == 0), hi_inv = (xg == 7);
    const float* mk   = masksAll + (size_t)cls * VOX;
    const float* wcls = cfr + cls*1029;          // uniform -> scalar loads
    float* Gc = G + (size_t)cls * VOX;

    issue_slice(mk, mxp, Mxp, zpg, FLf, 0,     z0-3, y0, lane, wid);
    issue_slice(mk, mxp, Mxp, zpg, FLf, BUF_F, z0-2, y0, lane, wid);

    float4 a0{},a1{},a2{},a3{},a4{},a5{},a6{};
    float4 g0m{},g0x{},g1m{},g1x{},g2m{},g2x{};  // 3-deep (m, mx) capture pipeline
    float hmn = 1e30f, hmx = -1e30f;
    int cur = 0;

    #pragma unroll 1
    for (int zi = z0 - 3; zi <= z0 + ZT + 2; ++zi){
        // exact wait: leave next-slice loads (+1 store once storing started) in flight
        const bool pst = (zi >= z0 + 4);
        if (wid == 3){ if (pst) asm volatile("s_waitcnt vmcnt(4)" ::: "memory");
                       else     asm volatile("s_waitcnt vmcnt(3)" ::: "memory"); }
        else         { if (pst) asm volatile("s_waitcnt vmcnt(5)" ::: "memory");
                       else     asm volatile("s_waitcnt vmcnt(4)" ::: "memory"); }
        __builtin_amdgcn_sched_barrier(0);
        __builtin_amdgcn_s_barrier();
        __builtin_amdgcn_sched_barrier(0);

        const bool cap = (zi >= z0 && zi < z0 + ZT);   // capture m/mx for plane zi
        float4 nm{}, nx{};

        const int lo = z0 + 3 - zi;                // okJ: J>=lo && J-lo<ZT (wave-uniform)
        const bool ok0 = (0>=lo) && (0-lo<ZT);
        const bool ok1 = (1>=lo) && (1-lo<ZT);
        const bool ok2 = (2>=lo) && (2-lo<ZT);
        const bool ok3 = (3>=lo) && (3-lo<ZT);
        const bool ok4 = (4>=lo) && (4-lo<ZT);
        const bool ok5 = (5>=lo) && (5-lo<ZT);
        const bool ok6 = (6>=lo) && (6-lo<ZT);

        __builtin_amdgcn_s_setprio(1);
        #pragma unroll 1
        for (int dy = 0; dy < 7; ++dy){
            const int r = y + dy;
            const float* Pm = FLf + cur*BUF_F + r*32;
            const float* Pa = Pm + PLANE_F;
            const float* Pb = Pa + PLANE_F;
            const int c0 = (xg > 0 ? xg-1 : 0)*4;
            const int c1 = xg*4;
            const int c2 = (xg < 7 ? xg+1 : 7)*4;
            const float4 M0 = *(const float4*)(Pm + c0);
            const float4 M1 = *(const float4*)(Pm + c1);
            const float4 M2 = *(const float4*)(Pm + c2);
            if (cap && dy == 3) nm = M1;            // M1 IS m[zi][y0+y][x0..x0+3]
            const float pm0 = lo_inv ? 0.f : M0.y;
            const float pm1 = lo_inv ? 0.f : M0.z;
            const float pm2 = lo_inv ? 0.f : M0.w;
            const float pm3 = M1.x, pm4 = M1.y, pm5 = M1.z, pm6 = M1.w;
            const float pm7 = hi_inv ? 0.f : M2.x;
            const float pm8 = hi_inv ? 0.f : M2.y;
            const float pm9 = hi_inv ? 0.f : M2.z;

            {   // t = 0: field mask*mx
                const float4 A0 = *(const float4*)(Pa + c0);
                const float4 A1 = *(const float4*)(Pa + c1);
                const float4 A2 = *(const float4*)(Pa + c2);
                if (cap && dy == 3) nx = A1;        // A1 IS mx[...]
                const float pa0 = pm0*A0.y, pa1 = pm1*A0.z, pa2 = pm2*A0.w;
                const float pa3 = pm3*A1.x, pa4 = pm4*A1.y, pa5 = pm5*A1.z, pa6 = pm6*A1.w;
                const float pa7 = pm7*A2.x, pa8 = pm8*A2.y, pa9 = pm9*A2.z;
                TGROUP4(pa, wcls)
            }
            {   // t = 1: field mask*Mx
                const float4 B0 = *(const float4*)(Pb + c0);
                const float4 B1 = *(const float4*)(Pb + c1);
                const float4 B2 = *(const float4*)(Pb + c2);
                const float pb0 = pm0*B0.y, pb1 = pm1*B0.z, pb2 = pm2*B0.w;
                const float pb3 = pm3*B1.x, pb4 = pm4*B1.y, pb5 = pm5*B1.z, pb6 = pm6*B1.w;
                const float pb7 = pm7*B2.x, pb8 = pm8*B2.y, pb9 = pm9*B2.z;
                TGROUP4(pb, wcls + 343)
            }
            // t = 2: field mask
            TGROUP4(pm, wcls + 686)
        }
        __builtin_amdgcn_s_setprio(0);

        __builtin_amdgcn_sched_barrier(0);
        __builtin_amdgcn_s_barrier();            // all waves done reading buf[cur]
        __builtin_amdgcn_sched_barrier(0);
        issue_slice(mk, mxp, Mxp, zpg, FLf, cur*BUF_F, zi+2, y0, lane, wid);
        __builtin_amdgcn_sched_barrier(0);

        if (zi >= z0 + 3){                       // finalize plane zo = zi-3 from saved regs
            const int zo = zi - 3;
            const int oidx = (zo*HH + (y0 + y))*WW + x0;
            float4 r1;
            r1.x = g0m.x/(1.f + expf(-a0.x));
            r1.y = g0m.y/(1.f + expf(-a0.y));
            r1.z = g0m.z/(1.f + expf(-a0.z));
            r1.w = g0m.w/(1.f + expf(-a0.w));
            *(float4*)(Gc + oidx) = r1;          // store AFTER issues (vmcnt order)
            float h0 = r1.x*g0x.x, h1 = r1.y*g0x.y, h2 = r1.z*g0x.z, h3 = r1.w*g0x.w;
            hmn = fminf(hmn, fminf(fminf(h0,h1), fminf(h2,h3)));
            hmx = fmaxf(hmx, fmaxf(fmaxf(h0,h1), fmaxf(h2,h3)));
        }
        // rotate accumulators and capture pipeline
        a0=a1; a1=a2; a2=a3; a3=a4; a4=a5; a5=a6;
        a6 = make_float4(0.f,0.f,0.f,0.f);
        g0m=g1m; g0x=g1x; g1m=g2m; g1x=g2x; g2m=nm; g2x=nx;
        cur ^= 1;
    }
    asm volatile("s_waitcnt vmcnt(0)" ::: "memory");  // drain dummy DMA before LDS dealloc

    #pragma unroll
    for (int off = 32; off > 0; off >>= 1){
        hmn = fminf(hmn, __shfl_xor(hmn, off));
        hmx = fmaxf(hmx, __shfl_xor(hmx, off));
    }
    if ((tid & 63) == 0){ r4[wid*2] = hmn; r4[wid*2+1] = hmx; }
    __syncthreads();
    if (tid == 0){
        float a = fminf(fminf(r4[0],r4[2]), fminf(r4[4],r4[6]));
        float b = fmaxf(fmaxf(r4[1],r4[3]), fmaxf(r4[5],r4[7]));
        atomicMin(&keys[cls],     keyOf(a));
        atomicMax(&keys[NCL+cls], keyOf(b));
    }
}

__global__ void k_thr(const unsigned* __restrict__ keys, float* __restrict__ hminA,
                      float* __restrict__ invR){
    int i = threadIdx.x;
    if (i < NCL){
        float hm = keyInv(keys[i]);
        float hM = keyInv(keys[NCL+i]);
        hminA[i] = hm;
        invR[i] = 1.f/(hM - hm);
    }
}

// ---- g = ma * (norm > 0.2), in place, float4 (4 voxels/thread) ----
__global__ __launch_bounds__(256) void k_region(float* G, const float* __restrict__ mx,
        const float* __restrict__ hminA, const float* __restrict__ invR)
{
    int i = blockIdx.y;
    int v = (blockIdx.x*256 + threadIdx.x)*4;
    float4 ma = *(float4*)(G + (size_t)i*VOX + v);
    float4 xv = *(const float4*)(mx + v);
    float hm = hminA[i], ir = invR[i];
    float4 r;
    r.x = ((ma.x*xv.x - hm)*ir > THRESV) ? ma.x : 0.f;
    r.y = ((ma.y*xv.y - hm)*ir > THRESV) ? ma.y : 0.f;
    r.z = ((ma.z*xv.z - hm)*ir > THRESV) ? ma.z : 0.f;
    r.w = ((ma.w*xv.w - hm)*ir > THRESV) ? ma.w : 0.f;
    *(float4*)(G + (size_t)i*VOX + v) = r;
}

// ---- per-(class,channel) sums; 512 blocks (2/CU), x staged via LDS transpose ----
__global__ __launch_bounds__(256) void k_stats(const float* __restrict__ x,
        const float* G, float* __restrict__ part)
{
    __shared__ float xt[64][65];
    int tid = threadIdx.x;
    int c = tid & 63, vg = tid >> 6;
    int v0 = blockIdx.x * 1024;
    const int cc = tid >> 2;
    const int u0 = (tid & 3) * 16;
    float s1[NCL], s2[NCL];
    #pragma unroll
    for (int i=0;i<NCL;i++){ s1[i]=0.f; s2[i]=0.f; }
    #pragma unroll 1
    for (int t = 0; t < 16; ++t){
        int vb = v0 + t*64;
        __syncthreads();
        float ld[16];
        #pragma unroll
        for (int j = 0; j < 4; ++j){
            float4 f4 = *(const float4*)&x[(size_t)cc*VOX + vb + u0 + j*4];
            ld[j*4+0]=f4.x; ld[j*4+1]=f4.y; ld[j*4+2]=f4.z; ld[j*4+3]=f4.w;
        }
        #pragma unroll
        for (int j = 0; j < 16; ++j) xt[u0 + j][cc] = ld[j];
        __syncthreads();
        #pragma unroll 1
        for (int k = 0; k < 16; ++k){
            int vv = (k<<2) + vg;
            float xv = xt[vv][c];
            #pragma unroll
            for (int i=0;i<NCL;i++){
                float p = xv * G[i*VOX + vb + vv];
                s1[i] += p;
                s2[i] = fmaf(p, p, s2[i]);
            }
        }
    }
    __shared__ float red[4][64][2*NCL];
    #pragma unroll
    for (int i=0;i<NCL;i++){ red[vg][c][i] = s1[i]; red[vg][c][NCL+i] = s2[i]; }
    __syncthreads();
    if (vg == 0){
        float* dst = part + (size_t)blockIdx.x * (NCL*CCH*2);
        for (int i=0;i<NCL;i++){
            float a = red[0][c][i]+red[1][c][i]+red[2][c][i]+red[3][c][i];
            float b = red[0][c][NCL+i]+red[1][c][NCL+i]+red[2][c][NCL+i]+red[3][c][NCL+i];
            dst[i*CCH*2 + c*2 + 0] = a;
            dst[i*CCH*2 + c*2 + 1] = b;
        }
    }
}

// ---- finish stats over 512 partials ----
__global__ void k_params(const float* __restrict__ part, const float* __restrict__ gamma,
        const float* __restrict__ beta, float* __restrict__ aArr, float* __restrict__ kcArr)
{
    int i = blockIdx.x, c = threadIdx.x;
    float s1 = 0.f, s2 = 0.f;
    for (int b=0;b<512;b++){
        const float* p = part + (size_t)b*(NCL*CCH*2) + i*CCH*2 + c*2;
        s1 += p[0]; s2 += p[1];
    }
    float m   = s1 * (1.f/(float)VOX);
    float var = s2 * (1.f/(float)VOX) - m*m;
    float rinv = 1.f/sqrtf(var + EPSV);
    float gm = gamma[c];
    aArr[i*CCH + c]  = gm*rinv;
    kcArr[i*CCH + c] = beta[c] - m*rinv*gm;
}

__global__ void k_kcol(const float* __restrict__ kcArr, float* __restrict__ KcA){
    int c = threadIdx.x;
    if (c < CCH){
        float s = 0.f;
        for (int i=0;i<NCL;i++) s += kcArr[i*CCH + c];
        KcA[c] = s;
    }
}

// ---- final: 2 voxels/thread ----
__global__ __launch_bounds__(256) void k_final(const float* __restrict__ x,
        float* outAll, const float* __restrict__ aArr, const float* __restrict__ KcA)
{
    __shared__ float aL[NCL*CCH];
    __shared__ float KL[CCH];
    int tid = threadIdx.x;
    for (int q=tid; q<NCL*CCH; q+=256) aL[q] = aArr[q];
    if (tid < CCH) KL[tid] = KcA[tid];
    __syncthreads();
    int v = blockIdx.x*512 + tid;     // voxels v and v+256
    const float* Gp = outAll + (size_t)NCL*VOX;
    float g[NCL], h[NCL];
    #pragma unroll
    for (int i=0;i<NCL;i++){ g[i] = Gp[i*VOX + v]; h[i] = Gp[i*VOX + v + 256]; }
    #pragma unroll 4
    for (int c=0;c<CCH;c++){
        float P0 = 0.f, P1 = 0.f;
        #pragma unroll
        for (int i=0;i<NCL;i++){
            float a = aL[i*CCH + c];
            P0 = fmaf(g[i], a, P0);
            P1 = fmaf(h[i], a, P1);
        }
        float kl = KL[c];
        float xv0 = x[c*VOX + v];
        float xv1 = x[c*VOX + v + 256];
        outAll[c*VOX + v]       = fmaxf(0.f, fmaf(xv0, P0, kl));
        outAll[c*VOX + v + 256] = fmaxf(0.f, fmaf(xv1, P1, kl));
    }
}

extern "C" void kernel_launch(void* const* d_in, const int* in_sizes, int n_in,
                              void* d_out, int out_size, void* d_ws, size_t ws_size,
                              hipStream_t stream)
{
    const float* x     = (const float*)d_in[0];
    const float* clsw  = (const float*)d_in[1];
    const float* clsb  = (const float*)d_in[2];
    const float* cfr   = (const float*)d_in[3];
    const float* gamma = (const float*)d_in[4];
    const float* beta  = (const float*)d_in[5];

    float* out   = (float*)d_out;
    float* logit = out + (size_t)CCH*VOX;     // second output
    float* masks = out;                       // scratch: out[0 .. 20V)
    float* G     = out + (size_t)NCL*VOX;     // scratch: out[20V .. 40V)

    float* ws    = (float*)d_ws;
    float* mxp   = ws;                        // V
    float* Mxp   = ws + VOX;                  // V
    unsigned* keys = (unsigned*)(ws + 2*(size_t)VOX);   // 40
    float* hminA = ws + 2*(size_t)VOX + 64;   // 20
    float* invR  = hminA + NCL;               // 20
    float* part  = ws + 2*(size_t)VOX + 128;  // 512*2560
    float* aArr  = part + 512*(NCL*CCH*2);    // 1280
    float* kcArr = aArr + NCL*CCH;            // 1280
    float* KcA   = kcArr + NCL*CCH;           // 64
    float* zpg   = KcA + CCH;                 // 256 (zero page for OOB lanes)

    k_init<<<1, 64, 0, stream>>>(keys, zpg);
    k_logit_softmax<<<VOX/1024, 256, 0, stream>>>(x, clsw, clsb, masks, logit, mxp, Mxp);
    k_conv13<<<dim3(4, 16, NCL), 256, 0, stream>>>(masks, mxp, Mxp, cfr, G, keys, zpg);
    k_thr<<<1, 32, 0, stream>>>(keys, hminA, invR);
    k_region<<<dim3(VOX/1024, NCL), 256, 0, stream>>>(G, mxp, hminA, invR);
    k_stats<<<512, 256, 0, stream>>>(x, G, part);
    k_params<<<NCL, CCH, 0, stream>>>(part, gamma, beta, aArr, kcArr);
    k_kcol<<<1, CCH, 0, stream>>>(kcArr, KcA);
    k_final<<<VOX/512, 256, 0, stream>>>(x, out, aArr, KcA);
}

// Round 16
// 643.799 us; speedup vs baseline: 3.0371x; 1.7059x over previous
//
#include <hip/hip_runtime.h>

#define VOX (128*128*32)   // 524288 voxels
#define CCH 64
#define NCL 20
#define DD 128
#define HH 128
#define WW 32
#define ZT 8
#define EPSV 1e-5f
#define THRESV 0.2f

// ---- order-preserving float <-> uint key for atomic min/max ----
__device__ __forceinline__ unsigned keyOf(float f){
    unsigned u = __float_as_uint(f);
    return (u & 0x80000000u) ? ~u : (u | 0x80000000u);
}
__device__ __forceinline__ float keyInv(unsigned k){
    unsigned u = (k & 0x80000000u) ? (k & 0x7fffffffu) : ~k;
    return __uint_as_float(u);
}

__global__ void k_init(unsigned* keys, float* zpg){
    int i = threadIdx.x;
    if (i < NCL){ keys[i] = 0xFFFFFFFFu; keys[NCL+i] = 0u; }
    #pragma unroll
    for (int k = 0; k < 4; ++k) zpg[k*64 + i] = 0.f;
}

// ---- Pass A: logit + softmax + per-voxel mean/max, 4 voxels/thread (float4).
// NO unroll pragma on the c-loop: with launch_bounds(256,4)'s 128-VGPR cap,
// unroll-4 spilled the 80-VGPR acc[] array to scratch (r15: 555us, 1.1GB writes).
__global__ __launch_bounds__(256, 4) void k_logit_softmax(
    const float* __restrict__ x, const float* __restrict__ clsw,
    const float* __restrict__ clsb, float* __restrict__ masks,
    float* __restrict__ logit, float* __restrict__ mx, float* __restrict__ Mx)
{
    __shared__ float sw[NCL*CCH];
    __shared__ float sb[NCL];
    int tid = threadIdx.x;
    for (int q = tid; q < NCL*CCH; q += 256) sw[q] = clsw[q];
    if (tid < NCL) sb[tid] = clsb[tid];
    __syncthreads();
    const int v = blockIdx.x*1024 + tid*4;
    float4 acc[NCL];
    #pragma unroll
    for (int o=0;o<NCL;o++){ float b = sb[o]; acc[o] = make_float4(b,b,b,b); }
    float4 s  = make_float4(0.f,0.f,0.f,0.f);
    float4 mm = make_float4(-1e30f,-1e30f,-1e30f,-1e30f);
    for (int c=0;c<CCH;c++){
        float4 xv = *(const float4*)&x[(size_t)c*VOX + v];
        s.x += xv.x; s.y += xv.y; s.z += xv.z; s.w += xv.w;
        mm.x = fmaxf(mm.x, xv.x); mm.y = fmaxf(mm.y, xv.y);
        mm.z = fmaxf(mm.z, xv.z); mm.w = fmaxf(mm.w, xv.w);
        #pragma unroll
        for (int o=0;o<NCL;o++){
            float w = sw[o*CCH + c];
            acc[o].x = fmaf(xv.x, w, acc[o].x);
            acc[o].y = fmaf(xv.y, w, acc[o].y);
            acc[o].z = fmaf(xv.z, w, acc[o].z);
            acc[o].w = fmaf(xv.w, w, acc[o].w);
        }
    }
    *(float4*)&mx[v] = make_float4(s.x*(1.f/64.f), s.y*(1.f/64.f), s.z*(1.f/64.f), s.w*(1.f/64.f));
    *(float4*)&Mx[v] = mm;
    float4 lm = acc[0];
    #pragma unroll
    for (int o=1;o<NCL;o++){
        lm.x = fmaxf(lm.x, acc[o].x); lm.y = fmaxf(lm.y, acc[o].y);
        lm.z = fmaxf(lm.z, acc[o].z); lm.w = fmaxf(lm.w, acc[o].w);
    }
    float4 es = make_float4(0.f,0.f,0.f,0.f);
    #pragma unroll
    for (int o=0;o<NCL;o++){
        *(float4*)&logit[(size_t)o*VOX + v] = acc[o];
        float4 e;
        e.x = expf(acc[o].x - lm.x); e.y = expf(acc[o].y - lm.y);
        e.z = expf(acc[o].z - lm.z); e.w = expf(acc[o].w - lm.w);
        es.x += e.x; es.y += e.y; es.z += e.z; es.w += e.w;
        acc[o] = e;
    }
    float4 inv = make_float4(1.f/es.x, 1.f/es.y, 1.f/es.z, 1.f/es.w);
    #pragma unroll
    for (int o=0;o<NCL;o++){
        float4 r;
        r.x = acc[o].x*inv.x; r.y = acc[o].y*inv.y;
        r.z = acc[o].z*inv.z; r.w = acc[o].w*inv.w;
        *(float4*)&masks[(size_t)o*VOX + v] = r;
    }
}

// ---- Pass B: 32x32 tile, 4-wave blocks, fused finalize, setprio on FMA body ----
#define F4(A, WV, q0,q1,q2,q3) { A.x=fmaf(q0,WV,A.x); A.y=fmaf(q1,WV,A.y); \
                                 A.z=fmaf(q2,WV,A.z); A.w=fmaf(q3,WV,A.w); }
#define DZ4(A, WP, P) { \
    F4(A,(WP)[0], P##0,P##1,P##2,P##3) \
    F4(A,(WP)[1], P##1,P##2,P##3,P##4) \
    F4(A,(WP)[2], P##2,P##3,P##4,P##5) \
    F4(A,(WP)[3], P##3,P##4,P##5,P##6) \
    F4(A,(WP)[4], P##4,P##5,P##6,P##7) \
    F4(A,(WP)[5], P##5,P##6,P##7,P##8) \
    F4(A,(WP)[6], P##6,P##7,P##8,P##9) }

#define TGROUP4(P, WT) { \
    const float* wd_ = (WT) + dy*7; \
    if (ok6) DZ4(a6, wd_+0,   P) \
    if (ok5) DZ4(a5, wd_+49,  P) \
    if (ok4) DZ4(a4, wd_+98,  P) \
    if (ok3) DZ4(a3, wd_+147, P) \
    if (ok2) DZ4(a2, wd_+196, P) \
    if (ok1) DZ4(a1, wd_+245, P) \
    if (ok0) DZ4(a0, wd_+294, P) }

#define PLANE_F 1280     // 40 rows x 32 floats
#define BUF_F   3840     // 3 planes
#define LDS_F   7680     // 2 buffers

__device__ __forceinline__ void issue_slice(const float* mk, const float* mxp, const float* Mxp,
        const float* zpg, float* FLf, int bufF, int zi, int y0, int lane, int wid)
{
    const bool zok = (unsigned)zi < (unsigned)DD;
    const float* srcs[3] = { mk, mxp, Mxp };
    #pragma unroll
    for (int k = 0; k < 15; ++k){
        if ((k >> 2) != wid) continue;           // waves issue 4/4/4/3
        const int f = k/5, j = k%5;
        int Q   = j*64 + lane;
        int row = Q >> 3, xq = Q & 7;
        int gy  = y0 - 3 + row;
        const float* g;
        if (zok && row < 38 && (unsigned)gy < (unsigned)HH)
            g = srcs[f] + ((size_t)(zi*HH + gy)*32 + xq*4);
        else
            g = zpg + lane*4;
        float* l = FLf + bufF + f*PLANE_F + j*256;   // wave-uniform; HW adds lane*16B
        __builtin_amdgcn_global_load_lds(
            (const __attribute__((address_space(1))) void*)g,
            (__attribute__((address_space(3))) void*)l, 16, 0, 0);
    }
}

__global__ __launch_bounds__(256, 5) void k_conv13(const float* __restrict__ masksAll,
        const float* __restrict__ mxp, const float* __restrict__ Mxp,
        const float* __restrict__ cfr, float* __restrict__ G,
        unsigned* __restrict__ keys, const float* __restrict__ zpg)
{
    __shared__ __align__(16) float FLf[LDS_F];
    __shared__ float r4[8];
    const int y0  = blockIdx.x * 32;
    const int z0  = blockIdx.y * ZT;
    const int cls = blockIdx.z;
    const int tid = threadIdx.x;
    const int lane = tid & 63, wid = tid >> 6;
    const int y  = tid >> 3;          // 0..31
    const int xg = tid & 7;           // 0..7
    const int x0 = xg * 4;
    const bool lo_inv = (xg == 0), hi_inv = (xg == 7);
    const float* mk   = masksAll + (size_t)cls * VOX;
    const float* wcls = cfr + cls*1029;          // uniform -> scalar loads
    float* Gc = G + (size_t)cls * VOX;

    issue_slice(mk, mxp, Mxp, zpg, FLf, 0,     z0-3, y0, lane, wid);
    issue_slice(mk, mxp, Mxp, zpg, FLf, BUF_F, z0-2, y0, lane, wid);

    float4 a0{},a1{},a2{},a3{},a4{},a5{},a6{};
    float4 g0m{},g0x{},g1m{},g1x{},g2m{},g2x{};  // 3-deep (m, mx) capture pipeline
    float hmn = 1e30f, hmx = -1e30f;
    int cur = 0;

    #pragma unroll 1
    for (int zi = z0 - 3; zi <= z0 + ZT + 2; ++zi){
        // exact wait: leave next-slice loads (+1 store once storing started) in flight
        const bool pst = (zi >= z0 + 4);
        if (wid == 3){ if (pst) asm volatile("s_waitcnt vmcnt(4)" ::: "memory");
                       else     asm volatile("s_waitcnt vmcnt(3)" ::: "memory"); }
        else         { if (pst) asm volatile("s_waitcnt vmcnt(5)" ::: "memory");
                       else     asm volatile("s_waitcnt vmcnt(4)" ::: "memory"); }
        __builtin_amdgcn_sched_barrier(0);
        __builtin_amdgcn_s_barrier();
        __builtin_amdgcn_sched_barrier(0);

        const bool cap = (zi >= z0 && zi < z0 + ZT);   // capture m/mx for plane zi
        float4 nm{}, nx{};

        const int lo = z0 + 3 - zi;                // okJ: J>=lo && J-lo<ZT (wave-uniform)
        const bool ok0 = (0>=lo) && (0-lo<ZT);
        const bool ok1 = (1>=lo) && (1-lo<ZT);
        const bool ok2 = (2>=lo) && (2-lo<ZT);
        const bool ok3 = (3>=lo) && (3-lo<ZT);
        const bool ok4 = (4>=lo) && (4-lo<ZT);
        const bool ok5 = (5>=lo) && (5-lo<ZT);
        const bool ok6 = (6>=lo) && (6-lo<ZT);

        __builtin_amdgcn_s_setprio(1);
        #pragma unroll 1
        for (int dy = 0; dy < 7; ++dy){
            const int r = y + dy;
            const float* Pm = FLf + cur*BUF_F + r*32;
            const float* Pa = Pm + PLANE_F;
            const float* Pb = Pa + PLANE_F;
            const int c0 = (xg > 0 ? xg-1 : 0)*4;
            const int c1 = xg*4;
            const int c2 = (xg < 7 ? xg+1 : 7)*4;
            const float4 M0 = *(const float4*)(Pm + c0);
            const float4 M1 = *(const float4*)(Pm + c1);
            const float4 M2 = *(const float4*)(Pm + c2);
            if (cap && dy == 3) nm = M1;            // M1 IS m[zi][y0+y][x0..x0+3]
            const float pm0 = lo_inv ? 0.f : M0.y;
            const float pm1 = lo_inv ? 0.f : M0.z;
            const float pm2 = lo_inv ? 0.f : M0.w;
            const float pm3 = M1.x, pm4 = M1.y, pm5 = M1.z, pm6 = M1.w;
            const float pm7 = hi_inv ? 0.f : M2.x;
            const float pm8 = hi_inv ? 0.f : M2.y;
            const float pm9 = hi_inv ? 0.f : M2.z;

            {   // t = 0: field mask*mx
                const float4 A0 = *(const float4*)(Pa + c0);
                const float4 A1 = *(const float4*)(Pa + c1);
                const float4 A2 = *(const float4*)(Pa + c2);
                if (cap && dy == 3) nx = A1;        // A1 IS mx[...]
                const float pa0 = pm0*A0.y, pa1 = pm1*A0.z, pa2 = pm2*A0.w;
                const float pa3 = pm3*A1.x, pa4 = pm4*A1.y, pa5 = pm5*A1.z, pa6 = pm6*A1.w;
                const float pa7 = pm7*A2.x, pa8 = pm8*A2.y, pa9 = pm9*A2.z;
                TGROUP4(pa, wcls)
            }
            {   // t = 1: field mask*Mx
                const float4 B0 = *(const float4*)(Pb + c0);
                const float4 B1 = *(const float4*)(Pb + c1);
                const float4 B2 = *(const float4*)(Pb + c2);
                const float pb0 = pm0*B0.y, pb1 = pm1*B0.z, pb2 = pm2*B0.w;
                const float pb3 = pm3*B1.x, pb4 = pm4*B1.y, pb5 = pm5*B1.z, pb6 = pm6*B1.w;
                const float pb7 = pm7*B2.x, pb8 = pm8*B2.y, pb9 = pm9*B2.z;
                TGROUP4(pb, wcls + 343)
            }
            // t = 2: field mask
            TGROUP4(pm, wcls + 686)
        }
        __builtin_amdgcn_s_setprio(0);

        __builtin_amdgcn_sched_barrier(0);
        __builtin_amdgcn_s_barrier();            // all waves done reading buf[cur]
        __builtin_amdgcn_sched_barrier(0);
        issue_slice(mk, mxp, Mxp, zpg, FLf, cur*BUF_F, zi+2, y0, lane, wid);
        __builtin_amdgcn_sched_barrier(0);

        if (zi >= z0 + 3){                       // finalize plane zo = zi-3 from saved regs
            const int zo = zi - 3;
            const int oidx = (zo*HH + (y0 + y))*WW + x0;
            float4 r1;
            r1.x = g0m.x/(1.f + expf(-a0.x));
            r1.y = g0m.y/(1.f + expf(-a0.y));
            r1.z = g0m.z/(1.f + expf(-a0.z));
            r1.w = g0m.w/(1.f + expf(-a0.w));
            *(float4*)(Gc + oidx) = r1;          // store AFTER issues (vmcnt order)
            float h0 = r1.x*g0x.x, h1 = r1.y*g0x.y, h2 = r1.z*g0x.z, h3 = r1.w*g0x.w;
            hmn = fminf(hmn, fminf(fminf(h0,h1), fminf(h2,h3)));
            hmx = fmaxf(hmx, fmaxf(fmaxf(h0,h1), fmaxf(h2,h3)));
        }
        // rotate accumulators and capture pipeline
        a0=a1; a1=a2; a2=a3; a3=a4; a4=a5; a5=a6;
        a6 = make_float4(0.f,0.f,0.f,0.f);
        g0m=g1m; g0x=g1x; g1m=g2m; g1x=g2x; g2m=nm; g2x=nx;
        cur ^= 1;
    }
    asm volatile("s_waitcnt vmcnt(0)" ::: "memory");  // drain dummy DMA before LDS dealloc

    #pragma unroll
    for (int off = 32; off > 0; off >>= 1){
        hmn = fminf(hmn, __shfl_xor(hmn, off));
        hmx = fmaxf(hmx, __shfl_xor(hmx, off));
    }
    if ((tid & 63) == 0){ r4[wid*2] = hmn; r4[wid*2+1] = hmx; }
    __syncthreads();
    if (tid == 0){
        float a = fminf(fminf(r4[0],r4[2]), fminf(r4[4],r4[6]));
        float b = fmaxf(fmaxf(r4[1],r4[3]), fmaxf(r4[5],r4[7]));
        atomicMin(&keys[cls],     keyOf(a));
        atomicMax(&keys[NCL+cls], keyOf(b));
    }
}

__global__ void k_thr(const unsigned* __restrict__ keys, float* __restrict__ hminA,
                      float* __restrict__ invR){
    int i = threadIdx.x;
    if (i < NCL){
        float hm = keyInv(keys[i]);
        float hM = keyInv(keys[NCL+i]);
        hminA[i] = hm;
        invR[i] = 1.f/(hM - hm);
    }
}

// ---- g = ma * (norm > 0.2), in place, float4 (4 voxels/thread) ----
__global__ __launch_bounds__(256) void k_region(float* G, const float* __restrict__ mx,
        const float* __restrict__ hminA, const float* __restrict__ invR)
{
    int i = blockIdx.y;
    int v = (blockIdx.x*256 + threadIdx.x)*4;
    float4 ma = *(float4*)(G + (size_t)i*VOX + v);
    float4 xv = *(const float4*)(mx + v);
    float hm = hminA[i], ir = invR[i];
    float4 r;
    r.x = ((ma.x*xv.x - hm)*ir > THRESV) ? ma.x : 0.f;
    r.y = ((ma.y*xv.y - hm)*ir > THRESV) ? ma.y : 0.f;
    r.z = ((ma.z*xv.z - hm)*ir > THRESV) ? ma.z : 0.f;
    r.w = ((ma.w*xv.w - hm)*ir > THRESV) ? ma.w : 0.f;
    *(float4*)(G + (size_t)i*VOX + v) = r;
}

// ---- per-(class,channel) sums; 512 blocks (2/CU), x staged via LDS transpose ----
__global__ __launch_bounds__(256) void k_stats(const float* __restrict__ x,
        const float* G, float* __restrict__ part)
{
    __shared__ float xt[64][65];
    int tid = threadIdx.x;
    int c = tid & 63, vg = tid >> 6;
    int v0 = blockIdx.x * 1024;
    const int cc = tid >> 2;
    const int u0 = (tid & 3) * 16;
    float s1[NCL], s2[NCL];
    #pragma unroll
    for (int i=0;i<NCL;i++){ s1[i]=0.f; s2[i]=0.f; }
    #pragma unroll 1
    for (int t = 0; t < 16; ++t){
        int vb = v0 + t*64;
        __syncthreads();
        float ld[16];
        #pragma unroll
        for (int j = 0; j < 4; ++j){
            float4 f4 = *(const float4*)&x[(size_t)cc*VOX + vb + u0 + j*4];
            ld[j*4+0]=f4.x; ld[j*4+1]=f4.y; ld[j*4+2]=f4.z; ld[j*4+3]=f4.w;
        }
        #pragma unroll
        for (int j = 0; j < 16; ++j) xt[u0 + j][cc] = ld[j];
        __syncthreads();
        #pragma unroll 1
        for (int k = 0; k < 16; ++k){
            int vv = (k<<2) + vg;
            float xv = xt[vv][c];
            #pragma unroll
            for (int i=0;i<NCL;i++){
                float p = xv * G[i*VOX + vb + vv];
                s1[i] += p;
                s2[i] = fmaf(p, p, s2[i]);
            }
        }
    }
    __shared__ float red[4][64][2*NCL];
    #pragma unroll
    for (int i=0;i<NCL;i++){ red[vg][c][i] = s1[i]; red[vg][c][NCL+i] = s2[i]; }
    __syncthreads();
    if (vg == 0){
        float* dst = part + (size_t)blockIdx.x * (NCL*CCH*2);
        for (int i=0;i<NCL;i++){
            float a = red[0][c][i]+red[1][c][i]+red[2][c][i]+red[3][c][i];
            float b = red[0][c][NCL+i]+red[1][c][NCL+i]+red[2][c][NCL+i]+red[3][c][NCL+i];
            dst[i*CCH*2 + c*2 + 0] = a;
            dst[i*CCH*2 + c*2 + 1] = b;
        }
    }
}

// ---- finish stats over 512 partials ----
__global__ void k_params(const float* __restrict__ part, const float* __restrict__ gamma,
        const float* __restrict__ beta, float* __restrict__ aArr, float* __restrict__ kcArr)
{
    int i = blockIdx.x, c = threadIdx.x;
    float s1 = 0.f, s2 = 0.f;
    for (int b=0;b<512;b++){
        const float* p = part + (size_t)b*(NCL*CCH*2) + i*CCH*2 + c*2;
        s1 += p[0]; s2 += p[1];
    }
    float m   = s1 * (1.f/(float)VOX);
    float var = s2 * (1.f/(float)VOX) - m*m;
    float rinv = 1.f/sqrtf(var + EPSV);
    float gm = gamma[c];
    aArr[i*CCH + c]  = gm*rinv;
    kcArr[i*CCH + c] = beta[c] - m*rinv*gm;
}

__global__ void k_kcol(const float* __restrict__ kcArr, float* __restrict__ KcA){
    int c = threadIdx.x;
    if (c < CCH){
        float s = 0.f;
        for (int i=0;i<NCL;i++) s += kcArr[i*CCH + c];
        KcA[c] = s;
    }
}

// ---- final: 2 voxels/thread ----
__global__ __launch_bounds__(256) void k_final(const float* __restrict__ x,
        float* outAll, const float* __restrict__ aArr, const float* __restrict__ KcA)
{
    __shared__ float aL[NCL*CCH];
    __shared__ float KL[CCH];
    int tid = threadIdx.x;
    for (int q=tid; q<NCL*CCH; q+=256) aL[q] = aArr[q];
    if (tid < CCH) KL[tid] = KcA[tid];
    __syncthreads();
    int v = blockIdx.x*512 + tid;     // voxels v and v+256
    const float* Gp = outAll + (size_t)NCL*VOX;
    float g[NCL], h[NCL];
    #pragma unroll
    for (int i=0;i<NCL;i++){ g[i] = Gp[i*VOX + v]; h[i] = Gp[i*VOX + v + 256]; }
    #pragma unroll 4
    for (int c=0;c<CCH;c++){
        float P0 = 0.f, P1 = 0.f;
        #pragma unroll
        for (int i=0;i<NCL;i++){
            float a = aL[i*CCH + c];
            P0 = fmaf(g[i], a, P0);
            P1 = fmaf(h[i], a, P1);
        }
        float kl = KL[c];
        float xv0 = x[c*VOX + v];
        float xv1 = x[c*VOX + v + 256];
        outAll[c*VOX + v]       = fmaxf(0.f, fmaf(xv0, P0, kl));
        outAll[c*VOX + v + 256] = fmaxf(0.f, fmaf(xv1, P1, kl));
    }
}

extern "C" void kernel_launch(void* const* d_in, const int* in_sizes, int n_in,
                              void* d_out, int out_size, void* d_ws, size_t ws_size,
                              hipStream_t stream)
{
    const float* x     = (const float*)d_in[0];
    const float* clsw  = (const float*)d_in[1];
    const float* clsb  = (const float*)d_in[2];
    const float* cfr   = (const float*)d_in[3];
    const float* gamma = (const float*)d_in[4];
    const float* beta  = (const float*)d_in[5];

    float* out   = (float*)d_out;
    float* logit = out + (size_t)CCH*VOX;     // second output
    float* masks = out;                       // scratch: out[0 .. 20V)
    float* G     = out + (size_t)NCL*VOX;     // scratch: out[20V .. 40V)

    float* ws    = (float*)d_ws;
    float* mxp   = ws;                        // V
    float* Mxp   = ws + VOX;                  // V
    unsigned* keys = (unsigned*)(ws + 2*(size_t)VOX);   // 40
    float* hminA = ws + 2*(size_t)VOX + 64;   // 20
    float* invR  = hminA + NCL;               // 20
    float* part  = ws + 2*(size_t)VOX + 128;  // 512*2560
    float* aArr  = part + 512*(NCL*CCH*2);    // 1280
    float* kcArr = aArr + NCL*CCH;            // 1280
    float* KcA   = kcArr + NCL*CCH;           // 64
    float* zpg   = KcA + CCH;                 // 256 (zero page for OOB lanes)

    k_init<<<1, 64, 0, stream>>>(keys, zpg);
    k_logit_softmax<<<VOX/1024, 256, 0, stream>>>(x, clsw, clsb, masks, logit, mxp, Mxp);
    k_conv13<<<dim3(4, 16, NCL), 256, 0, stream>>>(masks, mxp, Mxp, cfr, G, keys, zpg);
    k_thr<<<1, 32, 0, stream>>>(keys, hminA, invR);
    k_region<<<dim3(VOX/1024, NCL), 256, 0, stream>>>(G, mxp, hminA, invR);
    k_stats<<<512, 256, 0, stream>>>(x, G, part);
    k_params<<<NCL, CCH, 0, stream>>>(part, gamma, beta, aArr, kcArr);
    k_kcol<<<1, CCH, 0, stream>>>(kcArr, KcA);
    k_final<<<VOX/512, 256, 0, stream>>>(x, out, aArr, KcA);
}